// Round 1
// baseline (160.174 us; speedup 1.0000x reference)
//
#include <hip/hip_runtime.h>

// Problem constants (from setup_inputs: B=8, C=128, H=128, W=256, disp in [-4,4])
#define CC   128
#define HH   128
#define WW   256
#define BB   8
#define HWS  (HH * WW)        // 32768
#define TH   16               // tile rows per block
#define TW   64               // tile cols per block
#define SROWS (TH + 8)        // 24  (4 halo each side)
#define SCOLS (TW + 8)        // 72
#define STILE (SROWS * SCOLS) // 1728
#define NTHR 768              // 3 dy-groups x 256 pixel-threads (16 rows x 16 x-chunks)

typedef float f4 __attribute__((ext_vector_type(4)));

__global__ __launch_bounds__(NTHR)
void corr_kernel(const float* __restrict__ first,
                 const float* __restrict__ second,
                 float* __restrict__ out)
{
    // double-buffered second-tile (zero-padded halo), 2*1728*4 = 13.8 KB
    __shared__ float s_lds[2 * STILE];

    const int tid = threadIdx.x;
    const int g   = tid >> 8;          // dy-group 0..2 (handles dy = 3g-4 .. 3g-2)
    const int p   = tid & 255;
    const int r   = p >> 4;            // local row 0..15
    const int xq  = p & 15;            // x-chunk 0..15
    const int x0  = xq << 2;           // local x of pixel 0 (multiple of 4)

    const int bx = blockIdx.x * TW;
    const int by = blockIdx.y * TH;
    const int b  = blockIdx.z;

    const int y  = by + r;             // global row of this thread's pixels
    const int xg = bx + x0;            // global col of pixel 0

    // ---- staging setup: each thread stages up to 3 of the 1728 tile elements
    const int i0 = tid;
    const int i1 = tid + NTHR;
    const int i2 = tid + 2 * NTHR;     // valid only if < STILE (tid < 192)

    const int sr0 = i0 / SCOLS, sc0 = i0 % SCOLS;
    const int sr1 = i1 / SCOLS, sc1 = i1 % SCOLS;
    const int sr2 = i2 / SCOLS, sc2 = i2 % SCOLS;

    const int ys0 = by - 4 + sr0, xs0 = bx - 4 + sc0;
    const int ys1 = by - 4 + sr1, xs1 = bx - 4 + sc1;
    const int ys2 = by - 4 + sr2, xs2 = bx - 4 + sc2;

    const bool v0 = ((unsigned)ys0 < HH) && ((unsigned)xs0 < WW);
    const bool v1 = ((unsigned)ys1 < HH) && ((unsigned)xs1 < WW);
    const bool v2 = (i2 < STILE) && ((unsigned)ys2 < HH) && ((unsigned)xs2 < WW);

    const float* sbase = second + (long)b * CC * HWS;
    int go0 = v0 ? (ys0 * WW + xs0) : 0;   // per-channel: + c*HWS
    int go1 = v1 ? (ys1 * WW + xs1) : 0;
    int go2 = v2 ? (ys2 * WW + xs2) : 0;

    // ---- accumulators: 3 dy-rows x 9 dx x 4 pixels
    float acc[3][9][4];
    #pragma unroll
    for (int a = 0; a < 3; ++a)
        #pragma unroll
        for (int d = 0; d < 9; ++d)
            #pragma unroll
            for (int q = 0; q < 4; ++q)
                acc[a][d][q] = 0.0f;

    // ---- prologue: stage channel 0 into buffer 0
    {
        float t0 = v0 ? sbase[go0] : 0.0f;
        float t1 = v1 ? sbase[go1] : 0.0f;
        float t2 = v2 ? sbase[go2] : 0.0f;
        s_lds[i0] = t0;
        s_lds[i1] = t1;
        if (i2 < STILE) s_lds[i2] = t2;
    }
    __syncthreads();

    const float* fptr = first + ((long)(b * CC) * HH + y) * WW + xg;

    int cur = 0;
    for (int c = 0; c < CC; ++c) {
        // issue next-channel staging loads EARLY (latency hides under compute)
        float t0 = 0.0f, t1 = 0.0f, t2 = 0.0f;
        const bool more = (c + 1 < CC);
        if (more) {
            const float* sb = sbase + (c + 1) * HWS;
            t0 = v0 ? sb[go0] : 0.0f;
            t1 = v1 ? sb[go1] : 0.0f;
            t2 = v2 ? sb[go2] : 0.0f;
        }

        // first: direct global, coalesced b128 (L1 serves the 3x dy-group reuse)
        f4 fv = *(const f4*)fptr;
        fptr += HWS;

        // compute from current LDS buffer
        const float* sb_lds = &s_lds[cur * STILE];
        #pragma unroll
        for (int r3 = 0; r3 < 3; ++r3) {
            const int srow = r + g * 3 + r3;   // = r + (dy+4), in [0,23]
            const f4* wp = (const f4*)&sb_lds[srow * SCOLS + x0];
            f4 wa = wp[0];
            f4 wb = wp[1];
            f4 wc = wp[2];
            float w[12];
            w[0] = wa[0]; w[1]  = wa[1]; w[2]  = wa[2]; w[3]  = wa[3];
            w[4] = wb[0]; w[5]  = wb[1]; w[6]  = wb[2]; w[7]  = wb[3];
            w[8] = wc[0]; w[9]  = wc[1]; w[10] = wc[2]; w[11] = wc[3];
            #pragma unroll
            for (int dxi = 0; dxi < 9; ++dxi) {
                #pragma unroll
                for (int px = 0; px < 4; ++px) {
                    acc[r3][dxi][px] = fmaf(fv[px], w[dxi + px], acc[r3][dxi][px]);
                }
            }
        }

        // write next channel into the other buffer, then one barrier
        if (more) {
            const int nb = (cur ^ 1) * STILE;
            s_lds[nb + i0] = t0;
            s_lds[nb + i1] = t1;
            if (i2 < STILE) s_lds[nb + i2] = t2;
        }
        __syncthreads();
        cur ^= 1;
    }

    // ---- epilogue: scale by 1/C and store 27 b128s
    const float scale = 1.0f / (float)CC;
    #pragma unroll
    for (int r3 = 0; r3 < 3; ++r3) {
        #pragma unroll
        for (int dxi = 0; dxi < 9; ++dxi) {
            const int d = (g * 3 + r3) * 9 + dxi;   // (dy+4)*9 + (dx+4)
            f4 o;
            o[0] = acc[r3][dxi][0] * scale;
            o[1] = acc[r3][dxi][1] * scale;
            o[2] = acc[r3][dxi][2] * scale;
            o[3] = acc[r3][dxi][3] * scale;
            *(f4*)(out + (long)(b * 81 + d) * HWS + y * WW + xg) = o;
        }
    }
}

extern "C" void kernel_launch(void* const* d_in, const int* in_sizes, int n_in,
                              void* d_out, int out_size, void* d_ws, size_t ws_size,
                              hipStream_t stream) {
    const float* first  = (const float*)d_in[0];
    const float* second = (const float*)d_in[1];
    float* out = (float*)d_out;

    dim3 grid(WW / TW, HH / TH, BB);   // (4, 8, 8) = 256 blocks, 1 per CU
    corr_kernel<<<grid, NTHR, 0, stream>>>(first, second, out);
}